// Round 1
// baseline (840.411 us; speedup 1.0000x reference)
//
#include <hip/hip_runtime.h>

#define NROWS (2048 * 128)
#define D_IN 128
#define D1 96
#define D2 72
#define D3 64
#define BLK 256
#define KC 32
#define EPSF 1e-8f

__global__ __launch_bounds__(BLK, 2)
void fused_mlp(const float* __restrict__ x,
               const float* __restrict__ W1, const float* __restrict__ b1,
               const float* __restrict__ W2, const float* __restrict__ b2,
               const float* __restrict__ W3, const float* __restrict__ b3,
               float* __restrict__ acc /* [65]: s[64] then uu */)
{
    __shared__ float xs[BLK][KC + 1];      // 256 x 33 -> 2-way bank aliasing (free)
    __shared__ float sred[BLK / 64][D3];   // per-wave partial s
    __shared__ float uured[BLK / 64];      // per-wave partial uu

    const int tid  = threadIdx.x;
    const int lane = tid & 63;
    const int wv   = tid >> 6;

    float h1[D1];
#pragma unroll
    for (int o = 0; o < D1; ++o) h1[o] = b1[o];

    // ---- layer 1: k-chunked, x staged via LDS (coalesced global reads) ----
    for (int kc = 0; kc < D_IN; kc += KC) {
        __syncthreads();
        {
            const int r_sub = tid >> 3;         // 0..31
            const int c4    = (tid & 7) * 4;    // 0,4,...,28
#pragma unroll
            for (int p = 0; p < 8; ++p) {
                const int r = p * 32 + r_sub;
                const size_t gidx = (size_t)(blockIdx.x * BLK + r) * D_IN + kc + c4;
                const float4 v = *reinterpret_cast<const float4*>(&x[gidx]);
                xs[r][c4 + 0] = v.x; xs[r][c4 + 1] = v.y;
                xs[r][c4 + 2] = v.z; xs[r][c4 + 3] = v.w;
            }
        }
        __syncthreads();

        float xr[KC];
#pragma unroll
        for (int k = 0; k < KC; ++k) xr[k] = xs[tid][k];

#pragma unroll
        for (int o = 0; o < D1; ++o) {
            float a = h1[o];
#pragma unroll
            for (int k = 0; k < KC; ++k)
                a = fmaf(W1[o * D_IN + kc + k], xr[k], a);   // uniform addr -> s_load
            h1[o] = a;
        }
    }
#pragma unroll
    for (int o = 0; o < D1; ++o) h1[o] = fmaxf(h1[o], 0.f);

    // ---- layer 2 ----
    float h2[D2];
#pragma unroll
    for (int o = 0; o < D2; ++o) {
        float a = b2[o];
#pragma unroll
        for (int k = 0; k < D1; ++k)
            a = fmaf(W2[o * D1 + k], h1[k], a);
        h2[o] = fmaxf(a, 0.f);
    }

    // ---- layer 3 + row norm ----
    float f[D3];
    float ff = 0.f;
#pragma unroll
    for (int o = 0; o < D3; ++o) {
        float a = b3[o];
#pragma unroll
        for (int k = 0; k < D2; ++k)
            a = fmaf(W3[o * D2 + k], h2[k], a);
        f[o] = a;
        ff = fmaf(a, a, ff);
    }
    const float nrm = fmaxf(sqrtf(ff), EPSF);
    const float inv = 1.f / nrm;
    const float uu  = ff * inv * inv;   // ~1.0 unless norm < eps

    // ---- wave-level reduction: s[j] = sum over rows of u[j] ----
    float su = 0.f;   // lane l ends holding wave-sum of u[l]
#pragma unroll
    for (int j = 0; j < D3; ++j) {
        float v = f[j] * inv;
#pragma unroll
        for (int off = 32; off > 0; off >>= 1)
            v += __shfl_xor(v, off, 64);
        if (lane == j) su = v;
    }
    float uv = uu;
#pragma unroll
    for (int off = 32; off > 0; off >>= 1)
        uv += __shfl_xor(uv, off, 64);

    sred[wv][lane] = su;
    if (lane == 0) uured[wv] = uv;
    __syncthreads();

    // ---- block-level reduce + one atomic set per block ----
    if (tid < D3) {
        float t = sred[0][tid] + sred[1][tid] + sred[2][tid] + sred[3][tid];
        atomicAdd(&acc[tid], t);
    }
    if (tid == 0) {
        float t = uured[0] + uured[1] + uured[2] + uured[3];
        atomicAdd(&acc[D3], t);
    }
}

__global__ void finalize_k(const float* __restrict__ acc, float* __restrict__ out)
{
    float s = acc[threadIdx.x];     // 64 threads, lane j holds s[j]
    float d = s * s;
#pragma unroll
    for (int off = 32; off > 0; off >>= 1)
        d += __shfl_xor(d, off, 64);
    if (threadIdx.x == 0)
        out[0] = 0.5f * (d - acc[D3]) / (float)NROWS;
}

extern "C" void kernel_launch(void* const* d_in, const int* in_sizes, int n_in,
                              void* d_out, int out_size, void* d_ws, size_t ws_size,
                              hipStream_t stream)
{
    const float* x  = (const float*)d_in[0];
    const float* W1 = (const float*)d_in[1];
    const float* b1 = (const float*)d_in[2];
    const float* W2 = (const float*)d_in[3];
    const float* b2 = (const float*)d_in[4];
    const float* W3 = (const float*)d_in[5];
    const float* b3 = (const float*)d_in[6];

    float* acc = (float*)d_ws;                       // 65 floats
    hipMemsetAsync(acc, 0, 65 * sizeof(float), stream);

    fused_mlp<<<NROWS / BLK, BLK, 0, stream>>>(x, W1, b1, W2, b2, W3, b3, acc);
    finalize_k<<<1, 64, 0, stream>>>(acc, (float*)d_out);
}